// Round 7
// baseline (7720.712 us; speedup 1.0000x reference)
//
#include <hip/hip_runtime.h>
#include <stdint.h>
#include <stddef.h>

#define T_LEN  512
#define BATCH  64
#define NTAG   13
#define CTS    128     // super-chunk length
#define NSC    4       // number of super-chunks

__device__ __forceinline__ float sigm(float x) { return 1.0f / (1.0f + expf(-x)); }

// ---------------------------------------------------------------------------
// xg slice: 4 gate rows (one h-unit r4, gates i|f|g|o) x 1 sample, k=0..255
// strictly ascending fma chain — identical summation order to the old
// xg_gemm4, so the result is bit-identical. Raw sums (bias added later).
// ---------------------------------------------------------------------------
__device__ __forceinline__ void xg_compute(
    const float* __restrict__ wih,   // [32][260] flat
    const float* __restrict__ er,    // e row [260]
    float* __restrict__ xgout,       // [32][17] flat
    int r4, int s)
{
    const float* w0 = wih + (size_t)(     r4) * 260;
    const float* w1 = wih + (size_t)( 8 + r4) * 260;
    const float* w2 = wih + (size_t)(16 + r4) * 260;
    const float* w3 = wih + (size_t)(24 + r4) * 260;
    float a0 = 0.f, a1 = 0.f, a2 = 0.f, a3 = 0.f;
#pragma unroll 8
    for (int k = 0; k < 256; k += 4) {
        float4 e4 = *(const float4*)&er[k];
        float4 q;
        q = *(const float4*)&w0[k]; a0 += q.x*e4.x; a0 += q.y*e4.y; a0 += q.z*e4.z; a0 += q.w*e4.w;
        q = *(const float4*)&w1[k]; a1 += q.x*e4.x; a1 += q.y*e4.y; a1 += q.z*e4.z; a1 += q.w*e4.w;
        q = *(const float4*)&w2[k]; a2 += q.x*e4.x; a2 += q.y*e4.y; a2 += q.z*e4.z; a2 += q.w*e4.w;
        q = *(const float4*)&w3[k]; a3 += q.x*e4.x; a3 += q.y*e4.y; a3 += q.z*e4.z; a3 += q.w*e4.w;
    }
    xgout[(size_t)(     r4) * 17 + s] = a0;
    xgout[(size_t)( 8 + r4) * 17 + s] = a1;
    xgout[(size_t)(16 + r4) * 17 + s] = a2;
    xgout[(size_t)(24 + r4) * 17 + s] = a3;
}

// ---------------------------------------------------------------------------
// Fused persistent LSTM over a 128-step super-chunk. Sync protocol is
// byte-identical to R5/R11 (store -> drain barrier -> flag -> poll wave ->
// barrier -> coalesced reload -> barrier; relaxed agent-scope atomics,
// parity double-buffer, monotonic sc). NEW (R12): the input-side GEMM is
// computed in-kernel by waves 2-3 inside the poll window:
//   B2 -> nonlin/store (w0/w1)  -> B_d -> flag; [w0: poll | w2/w3: xg(t+1)]
//   -> B_p -> [w0/w1: h reload + e(t+2) LDS write] -> B3
// e tiles double-buffered, prefetched 2 steps ahead (global loads issued at
// top of loop, drained under the hh GEMM). W_ih resident in LDS.
// ---------------------------------------------------------------------------
__global__ __launch_bounds__(256) void lstm_fused(
    const int* __restrict__ x, const float* __restrict__ emb,
    const float* __restrict__ w_hh_f, const float* __restrict__ w_hh_b,
    const float* __restrict__ w_ih_f, const float* __restrict__ w_ih_b,
    const float* __restrict__ b_ih_f, const float* __restrict__ b_hh_f,
    const float* __restrict__ b_ih_b, const float* __restrict__ b_hh_b,
    float* h_ex, float* c_state, float* h_all, int* flags, int sch)
{
    const int tid = threadIdx.x;
    const int bid = blockIdx.x;
    const int dg    = bid & 7;
    const int slice = bid >> 3;      // 0..31
    const int dir = dg & 1;
    const int grp = dg >> 1;
    const int h_base = slice * 8;
    const int sbase  = grp * 16;

    __shared__ __align__(16) float w_lds[32][260];     // W_hh rows
    __shared__ __align__(16) float wih_lds[32][260];   // W_ih rows
    __shared__ __align__(16) float h_lds[16][260];
    __shared__ __align__(16) float e_lds[2][16][260];  // e tiles, dbuf by tl&1
    __shared__ __align__(16) float red[7][32][20];
    __shared__ float gatebuf[32][17];
    __shared__ float xg_lds[2][32][17];                // xg raw sums, dbuf

    const float* Whh = dir ? w_hh_b : w_hh_f;
    const float* Wih = dir ? w_ih_b : w_ih_f;
    const float* bi  = dir ? b_ih_b : b_ih_f;
    const float* bh  = dir ? b_hh_b : b_hh_f;

    const int tA = (dir ? (NSC - 1 - sch) : sch) * CTS;   // chunk time base
    // glob_t(L) = tA + (dir ? CTS-1-L : L)

    for (int idx = tid; idx < 2048; idx += 256) {     // f4 weight fills
        int f  = idx << 2;
        int rr = f >> 8;
        int c4 = f & 255;
        int row = (rr >> 3) * 256 + h_base + (rr & 7);
        *(float4*)&w_lds[rr][c4]   = *(const float4*)&Whh[(size_t)row * 256 + c4];
        *(float4*)&wih_lds[rr][c4] = *(const float4*)&Wih[(size_t)row * 256 + c4];
    }

    // nonlin-phase mapping (tid<128): ih lane-fastest for coalesced stores
    const int ih_g = tid & 7;
    const int s_g  = tid >> 3;       // 0..15 (for tid<128)
    float c_val = 0.0f;
    float bias_g[4] = {0.f, 0.f, 0.f, 0.f};
    if (tid < 128) {
        c_val = c_state[(size_t)(dir * 64 + sbase + s_g) * 256 + h_base + ih_g];
#pragma unroll
        for (int q = 0; q < 4; q++) {
            int g = q * 256 + h_base + ih_g;
            bias_g[q] = bi[g] + bh[g];
        }
        // e warmup: local steps 0 and 1
#pragma unroll
        for (int L = 0; L < 2; L++) {
            int tg  = tA + (dir ? (CTS - 1 - L) : L);
            int tok = x[(sbase + s_g) * T_LEN + tg];
            const float4* src = (const float4*)&emb[(size_t)tok * 256 + ih_g * 32];
            float4* dst = (float4*)&e_lds[L][s_g][ih_g * 32];
#pragma unroll
            for (int j = 0; j < 8; j++) dst[j] = src[j];
        }
    }

    {   // initial h fill from parity-0 buffer (prior super-chunk ends at
        // even sc; sch 0 reads memset zeros). Kernel boundary orders this.
        const float* base = &h_ex[((size_t)dg * 16) * 256];
#pragma unroll
        for (int i = 0; i < 8; i++) {
            int pos = tid + 256 * i;         // 8-byte units
            int fo  = pos << 1;
            unsigned long long u64 = __hip_atomic_load(
                (const unsigned long long*)(base + fo), __ATOMIC_RELAXED, __HIP_MEMORY_SCOPE_AGENT);
            float2 v = __builtin_bit_cast(float2, u64);
            *(float2*)&h_lds[fo >> 8][fo & 255] = v;
        }
    }
    __syncthreads();

    // xg warmup for local step 0 (needs wih_lds + e_lds[0])
    if (tid >= 128) {
        int u = tid - 128;
        xg_compute(&wih_lds[0][0], &e_lds[0][u & 15][0], &xg_lds[0][0][0], u >> 4, u & 15);
    }
    __syncthreads();

    const int kc   = tid >> 5;       // 0..7 k-split
    const int tile = tid & 31;
    const int gt = tile >> 2;        // rows gt + 8*gi
    const int st = tile & 3;         // samples st + 4*si
    const float* wr[4] = { &w_lds[gt][0], &w_lds[8+gt][0], &w_lds[16+gt][0], &w_lds[24+gt][0] };
    const float* hr[4] = { &h_lds[st][0], &h_lds[4+st][0], &h_lds[8+st][0],  &h_lds[12+st][0] };

    float hv_prev = 0.0f;
    size_t ha_prev = 0;

#pragma unroll 1
    for (int tl = 0; tl < CTS; tl++) {
        const int t  = tA + (dir ? (CTS - 1 - tl) : tl);
        const int sc = sch * CTS + tl + 1;
        const int par = sc & 1;
        const int cb  = tl & 1;
        const bool epref = (tl + 2 < CTS);

        // top-of-loop issues (drain under the GEMM): h_all store of the
        // previous step + global loads of the e tile for step tl+2.
        float4 ereg[8];
        if (tid < 128) {
            if (tl > 0) h_all[ha_prev] = hv_prev;
            if (epref) {
                int t2  = tA + (dir ? (CTS - 1 - (tl + 2)) : (tl + 2));
                int tok = x[(sbase + s_g) * T_LEN + t2];
                const float4* src = (const float4*)&emb[(size_t)tok * 256 + ih_g * 32];
#pragma unroll
                for (int j = 0; j < 8; j++) ereg[j] = src[j];
            }
        }

        float acc[4][4];
#pragma unroll
        for (int gi = 0; gi < 4; gi++)
#pragma unroll
            for (int si = 0; si < 4; si++) acc[gi][si] = 0.0f;

        const int j0 = kc * 32;
#pragma unroll
        for (int m = 0; m < 8; m++) {
            const int jj = j0 + m * 4;
            float4 w4[4], h4[4];
#pragma unroll
            for (int i = 0; i < 4; i++) w4[i] = *(const float4*)(wr[i] + jj);
#pragma unroll
            for (int i = 0; i < 4; i++) h4[i] = *(const float4*)(hr[i] + jj);
#pragma unroll
            for (int gi = 0; gi < 4; gi++)
#pragma unroll
                for (int si = 0; si < 4; si++)
                    acc[gi][si] += w4[gi].x*h4[si].x + w4[gi].y*h4[si].y
                                 + w4[gi].z*h4[si].z + w4[gi].w*h4[si].w;
        }

        // single-phase 8->1 k-split reduction
        if (kc >= 1) {
#pragma unroll
            for (int gi = 0; gi < 4; gi++)
                *(float4*)&red[kc-1][tile][gi*4] =
                    make_float4(acc[gi][0], acc[gi][1], acc[gi][2], acc[gi][3]);
        }
        __syncthreads();                                   // B1
        if (kc == 0) {
#pragma unroll
            for (int p = 0; p < 7; p++)
#pragma unroll
                for (int gi = 0; gi < 4; gi++) {
                    float4 v = *(const float4*)&red[p][tile][gi*4];
                    acc[gi][0] += v.x; acc[gi][1] += v.y; acc[gi][2] += v.z; acc[gi][3] += v.w;
                }
#pragma unroll
            for (int gi = 0; gi < 4; gi++)
#pragma unroll
                for (int si = 0; si < 4; si++)
                    gatebuf[8*gi + gt][4*si + st] = acc[gi][si];
        }
        __syncthreads();                                   // B2

        if (tid < 128) {
            float xgi = xg_lds[cb][     ih_g][s_g] + bias_g[0];
            float xgf = xg_lds[cb][ 8 + ih_g][s_g] + bias_g[1];
            float xgg = xg_lds[cb][16 + ih_g][s_g] + bias_g[2];
            float xgo = xg_lds[cb][24 + ih_g][s_g] + bias_g[3];
            float gI = gatebuf[     ih_g][s_g] + xgi;
            float gF = gatebuf[ 8 + ih_g][s_g] + xgf;
            float gG = gatebuf[16 + ih_g][s_g] + xgg;
            float gO = gatebuf[24 + ih_g][s_g] + xgo;
            c_val = sigm(gF) * c_val + sigm(gI) * tanhf(gG);
            float hv = sigm(gO) * tanhf(c_val);
            // coalesced: lanes with consecutive ih -> 32-B segments
            __hip_atomic_store(&h_ex[(((size_t)par * 8 + dg) * 16 + s_g) * 256 + h_base + ih_g],
                               hv, __ATOMIC_RELAXED, __HIP_MEMORY_SCOPE_AGENT);
            hv_prev = hv;
            ha_prev = ((size_t)t * 64 + sbase + s_g) * 512 + dir * 256 + h_base + ih_g;
        }
        __syncthreads();   // B_d: vmcnt(0) drain -> h_ex committed

        if (tid == 0)
            __hip_atomic_store(&flags[dg * 32 + slice], sc, __ATOMIC_RELAXED, __HIP_MEMORY_SCOPE_AGENT);

        // poll window: w0 polls; w2/w3 compute xg for step tl+1 (independent
        // of h, hidden in the wait). w1 idles to B_p.
        if (tid >= 128) {
            if (tl + 1 < CTS) {
                int u = tid - 128;
                xg_compute(&wih_lds[0][0], &e_lds[(tl + 1) & 1][u & 15][0],
                           &xg_lds[(tl + 1) & 1][0][0], u >> 4, u & 15);
            }
        } else if (tid < 64) {
            const int* fp = &flags[dg * 32 + (tid & 31)];
            int spins = 0;
            int v = __hip_atomic_load(fp, __ATOMIC_RELAXED, __HIP_MEMORY_SCOPE_AGENT);
            while (__ballot(v < sc) != 0ull) {
                if (++spins > 8) __builtin_amdgcn_s_sleep(1);
                v = __hip_atomic_load(fp, __ATOMIC_RELAXED, __HIP_MEMORY_SCOPE_AGENT);
                if (spins > (1 << 20)) break;   // safety valve; co-residency guaranteed
            }
        }
        __syncthreads();                                   // B_p

        // reload window (w0/w1): coherent h reload + e(tl+2) LDS write
        if (tid < 128) {
            const float* base = &h_ex[(((size_t)par * 8 + dg) * 16) * 256];
#pragma unroll
            for (int i = 0; i < 16; i++) {
                int pos = tid + 128 * i;
                int fo  = pos << 1;
                unsigned long long u64 = __hip_atomic_load(
                    (const unsigned long long*)(base + fo), __ATOMIC_RELAXED, __HIP_MEMORY_SCOPE_AGENT);
                float2 v = __builtin_bit_cast(float2, u64);
                *(float2*)&h_lds[fo >> 8][fo & 255] = v;
            }
            if (epref) {
                float4* dst = (float4*)&e_lds[tl & 1][s_g][ih_g * 32];  // (tl+2)&1 == tl&1
#pragma unroll
                for (int j = 0; j < 8; j++) dst[j] = ereg[j];
            }
        }
        __syncthreads();                                   // B3
    }

    if (tid < 128) {
        h_all[ha_prev] = hv_prev;
        c_state[(size_t)(dir * 64 + sbase + s_g) * 256 + h_base + ih_g] = c_val;
    }
}

// ---------------------------------------------------------------------------
__global__ __launch_bounds__(256) void emis_kernel(
    const float* __restrict__ h_all, const float* __restrict__ w_out,
    const float* __restrict__ b_out, float* __restrict__ emis)
{
    const int row = blockIdx.x * 16 + (threadIdx.x >> 4);
    const int k   = threadIdx.x & 15;
    const float* hr = &h_all[(size_t)row * 512];
    const float* wr = &w_out[(size_t)(k < NTAG ? k : 0) * 512];
    float acc = 0.0f;
#pragma unroll 8
    for (int e = 0; e < 512; e += 4) {
        float4 h4 = *(const float4*)&hr[e];
        float4 w4 = *(const float4*)&wr[e];
        acc += h4.x*w4.x + h4.y*w4.y + h4.z*w4.z + h4.w*w4.w;
    }
    if (k < NTAG) emis[(size_t)row * NTAG + k] = acc + b_out[k];
}

// ---------------------------------------------------------------------------
__global__ __launch_bounds__(64) void viterbi_kernel(
    const float* __restrict__ emis, const float* __restrict__ start_trans,
    const float* __restrict__ end_trans, const float* __restrict__ trans,
    float* __restrict__ out)
{
    const int b = blockIdx.x;
    const int k = threadIdx.x;
    __shared__ float em[T_LEN * NTAG];
    __shared__ unsigned char bp[T_LEN][16];

    for (int t = k; t < T_LEN; t += 64) {
        const float* src = &emis[((size_t)t * 64 + b) * NTAG];
#pragma unroll
        for (int kk = 0; kk < NTAG; kk++)
            em[t * NTAG + kk] = src[kk];
    }
    __syncthreads();

    float tc[NTAG];
#pragma unroll
    for (int kp = 0; kp < NTAG; kp++)
        tc[kp] = (k < NTAG) ? trans[kp * NTAG + k] : 0.0f;

    float score = (k < NTAG) ? (start_trans[k] + em[k]) : -3.0e38f;

    for (int t = 1; t < T_LEN; t++) {
        float best = -3.0e38f;
        int bi = 0;
#pragma unroll
        for (int kp = 0; kp < NTAG; kp++) {
            float v = __shfl(score, kp) + tc[kp];
            if (v > best) { best = v; bi = kp; }   // strict > => first max (jnp.argmax)
        }
        if (k < NTAG) {
            score = best + em[t * NTAG + k];
            bp[t][k] = (unsigned char)bi;
        }
    }
    if (k < NTAG) score += end_trans[k];
    else score = -3.0e38f;
    __syncthreads();

    float bs = -3.0e38f;
    int tag = 0;
#pragma unroll
    for (int kk = 0; kk < NTAG; kk++) {
        float v = __shfl(score, kk);
        if (v > bs) { bs = v; tag = kk; }
    }
    if (k == 0) {
        out[32768 + b] = bs;
        int tg = tag;
        out[b * T_LEN + (T_LEN - 1)] = (float)tg;
        for (int t = T_LEN - 1; t >= 1; t--) {
            tg = bp[t][tg];
            out[b * T_LEN + t - 1] = (float)tg;
        }
    }
}

// ---------------------------------------------------------------------------
extern "C" void kernel_launch(void* const* d_in, const int* in_sizes, int n_in,
                              void* d_out, int out_size, void* d_ws, size_t ws_size,
                              hipStream_t stream)
{
    (void)in_sizes; (void)n_in; (void)out_size; (void)ws_size;
    const int*   x    = (const int*)  d_in[0];
    const float* emb  = (const float*)d_in[1];
    const float* wihf = (const float*)d_in[2];
    const float* whhf = (const float*)d_in[3];
    const float* bihf = (const float*)d_in[4];
    const float* bhhf = (const float*)d_in[5];
    const float* wihb = (const float*)d_in[6];
    const float* whhb = (const float*)d_in[7];
    const float* bihb = (const float*)d_in[8];
    const float* bhhb = (const float*)d_in[9];
    const float* wout = (const float*)d_in[10];
    const float* bout = (const float*)d_in[11];
    const float* stt  = (const float*)d_in[12];
    const float* ent  = (const float*)d_in[13];
    const float* trn  = (const float*)d_in[14];
    float* out = (float*)d_out;

    const size_t HALL_BYTES = (size_t)T_LEN * 64 * 512 * 4;   // 67.11 MB
    const size_t HEX_BYTES  = (size_t)2 * 8 * 16 * 256 * 4;   // 256 KB
    const size_t CST_BYTES  = (size_t)2 * 64 * 256 * 4;       // 128 KB
    const size_t EMIS_BYTES = (size_t)T_LEN * 64 * NTAG * 4;  // 1.70 MB
    const size_t FLAG_BYTES = 8 * 32 * 4;

    char* ws = (char*)d_ws;
    size_t off = 0;
    float* h_all = (float*)(ws + off); off += HALL_BYTES;
    float* h_ex  = (float*)(ws + off); off += HEX_BYTES;
    float* c_st  = (float*)(ws + off); off += CST_BYTES;
    float* emis  = (float*)(ws + off); off += EMIS_BYTES;
    int*   flags = (int*)  (ws + off); off += FLAG_BYTES;

    hipMemsetAsync(h_ex,  0, HEX_BYTES, stream);
    hipMemsetAsync(c_st,  0, CST_BYTES, stream);
    hipMemsetAsync(flags, 0, FLAG_BYTES, stream);

    for (int c = 0; c < NSC; c++)
        lstm_fused<<<256, 256, 0, stream>>>(x, emb, whhf, whhb, wihf, wihb,
                                            bihf, bhhf, bihb, bhhb,
                                            h_ex, c_st, h_all, flags, c);

    emis_kernel<<<2048, 256, 0, stream>>>(h_all, wout, bout, emis);
    viterbi_kernel<<<64, 64, 0, stream>>>(emis, stt, ent, trn, out);
}

// Round 8
// 3408.228 us; speedup vs baseline: 2.2653x; 2.2653x over previous
//
#include <hip/hip_runtime.h>
#include <stdint.h>
#include <stddef.h>

#define T_LEN  512
#define BATCH  64
#define NTAG   13
#define CT     64
#define NCHUNK 8
#define CTS    128     // super-chunk length
#define NSC    4       // number of super-chunks

__device__ __forceinline__ float sigm(float x) { return 1.0f / (1.0f + expf(-x)); }

// ---------------------------------------------------------------------------
// R13 Kernel 1: input-side GEMM for one 128-step SUPER-chunk (both dirs),
// software-pipelined: the global loads for slab k+1 are issued right after
// the LDS-write barrier of slab k and drain under slab k's 16x64-FMA
// compute. Same fma order as R11 -> bit-exact. R12's in-kernel xg fusion is
// fully reverted (LDS-port contention + fairness collapse).
// ---------------------------------------------------------------------------
__global__ __launch_bounds__(256) void xg_gemm4(
    const int* __restrict__ x, const float* __restrict__ emb,
    const float* __restrict__ w_ih_f, const float* __restrict__ w_ih_b,
    const float* __restrict__ b_ih_f, const float* __restrict__ b_hh_f,
    const float* __restrict__ b_ih_b, const float* __restrict__ b_hh_b,
    float* __restrict__ xg_ws, int sch)
{
    const int tid = threadIdx.x;
    const int mt = blockIdx.x;
    const int nt = blockIdx.y;           // 0..63
    const int d  = blockIdx.z;
    const int tbase = (d == 0 ? sch : (NSC - 1 - sch)) * CTS;
    const float* W  = (d == 0) ? w_ih_f : w_ih_b;
    const float* bi = (d == 0) ? b_ih_f : b_ih_b;
    const float* bh = (d == 0) ? b_hh_f : b_hh_b;

    __shared__ __align__(16) float Wl[16][132];
    __shared__ __align__(16) float El[16][132];
    __shared__ int tok[128];

    if (tid < 128) {
        int col = nt * 128 + tid;
        tok[tid] = x[(col & 63) * T_LEN + tbase + (col >> 6)];
    }
    __syncthreads();

    const int r  = tid >> 1;
    const int c8 = (tid & 1) * 8;
    const int tm = tid >> 4;
    const int tn = tid & 15;

    float acc[8][8];
#pragma unroll
    for (int i = 0; i < 8; i++)
#pragma unroll
        for (int jz = 0; jz < 8; jz++) acc[i][jz] = 0.0f;

    const float* wrow = &W[(size_t)(mt * 128 + r) * 256];
    const float* erow = &emb[(size_t)tok[r] * 256];

    // prologue: slab 0 -> regs
    float4 w0 = *(const float4*)&wrow[c8];
    float4 w1 = *(const float4*)&wrow[c8 + 4];
    float4 e0 = *(const float4*)&erow[c8];
    float4 e1 = *(const float4*)&erow[c8 + 4];

    for (int kb = 0; kb < 256; kb += 16) {
        __syncthreads();   // previous slab's compute done -> LDS reusable
        Wl[c8+0][r] = w0.x; Wl[c8+1][r] = w0.y; Wl[c8+2][r] = w0.z; Wl[c8+3][r] = w0.w;
        Wl[c8+4][r] = w1.x; Wl[c8+5][r] = w1.y; Wl[c8+6][r] = w1.z; Wl[c8+7][r] = w1.w;
        El[c8+0][r] = e0.x; El[c8+1][r] = e0.y; El[c8+2][r] = e0.z; El[c8+3][r] = e0.w;
        El[c8+4][r] = e1.x; El[c8+5][r] = e1.y; El[c8+6][r] = e1.z; El[c8+7][r] = e1.w;
        __syncthreads();

        if (kb + 16 < 256) {   // issue slab k+1 loads; drain under compute
            w0 = *(const float4*)&wrow[kb + 16 + c8];
            w1 = *(const float4*)&wrow[kb + 16 + c8 + 4];
            e0 = *(const float4*)&erow[kb + 16 + c8];
            e1 = *(const float4*)&erow[kb + 16 + c8 + 4];
        }

#pragma unroll
        for (int kk = 0; kk < 16; kk++) {
            float a[8], b[8];
            *(float4*)&a[0] = *(const float4*)&Wl[kk][tm*8];
            *(float4*)&a[4] = *(const float4*)&Wl[kk][tm*8+4];
            *(float4*)&b[0] = *(const float4*)&El[kk][tn*8];
            *(float4*)&b[4] = *(const float4*)&El[kk][tn*8+4];
#pragma unroll
            for (int i = 0; i < 8; i++)
#pragma unroll
                for (int jz = 0; jz < 8; jz++)
                    acc[i][jz] += a[i] * b[jz];
        }
    }

    const int colbase = nt * 128 + tn * 8;
    const int j  = colbase >> 6;         // local timestep 0..127
    const int b0 = colbase & 63;
#pragma unroll
    for (int gi = 0; gi < 8; gi++) {
        int g = mt * 128 + tm * 8 + gi;
        float bias = bi[g] + bh[g];
        float* dst = &xg_ws[(((size_t)(d * CTS + j) * 1024 + g) << 6) + b0];
        float4 v0 = make_float4(acc[gi][0]+bias, acc[gi][1]+bias, acc[gi][2]+bias, acc[gi][3]+bias);
        float4 v1 = make_float4(acc[gi][4]+bias, acc[gi][5]+bias, acc[gi][6]+bias, acc[gi][7]+bias);
        *(float4*)dst       = v0;
        *(float4*)(dst + 4) = v1;
    }
}

// ---------------------------------------------------------------------------
// R11 Kernel 2 (byte-identical): persistent chunked LSTM over a 128-step
// super-chunk. Protocol = R5 (flags + poll wave + coalesced reload, relaxed
// agent-scope atomics, parity double-buffer, monotonic sc). FROZEN.
// ---------------------------------------------------------------------------
__global__ __launch_bounds__(256) void lstm_chunk4(
    const float* __restrict__ xg_ws,
    const float* __restrict__ w_hh_f, const float* __restrict__ w_hh_b,
    float* h_ex, float* c_state, float* h_all, int* flags, int sch)
{
    const int tid = threadIdx.x;
    const int bid = blockIdx.x;
    const int dg    = bid & 7;
    const int slice = bid >> 3;      // 0..31
    const int dir = dg & 1;
    const int grp = dg >> 1;
    const int h_base = slice * 8;
    const int sbase  = grp * 16;

    __shared__ __align__(16) float w_lds[32][260];
    __shared__ __align__(16) float h_lds[16][260];
    __shared__ __align__(16) float red[7][32][20];
    __shared__ float gatebuf[32][17];

    const float* W = dir ? w_hh_b : w_hh_f;
    for (int idx = tid; idx < 2048; idx += 256) {     // f4 weight fill
        int f  = idx << 2;
        int rr = f >> 8;
        int c4 = f & 255;
        int row = (rr >> 3) * 256 + h_base + (rr & 7);
        *(float4*)&w_lds[rr][c4] = *(const float4*)&W[(size_t)row * 256 + c4];
    }

    // nonlin-phase mapping (tid<128): ih lane-fastest for coalesced stores
    const int ih_g = tid & 7;
    const int s_g  = tid >> 3;       // 0..15 (for tid<128)
    float c_val = 0.0f;
    if (tid < 128)
        c_val = c_state[(size_t)(dir * 64 + sbase + s_g) * 256 + h_base + ih_g];

    {   // initial h fill from parity-0 buffer (prior super-chunk ends at
        // sc = sch*128, even -> parity 0; sch 0 reads memset zeros)
        const float* base = &h_ex[((size_t)dg * 16) * 256];
#pragma unroll
        for (int i = 0; i < 8; i++) {
            int pos = tid + 256 * i;         // 8-byte units
            int fo  = pos << 1;
            unsigned long long u64 = __hip_atomic_load(
                (const unsigned long long*)(base + fo), __ATOMIC_RELAXED, __HIP_MEMORY_SCOPE_AGENT);
            float2 v = __builtin_bit_cast(float2, u64);
            *(float2*)&h_lds[fo >> 8][fo & 255] = v;
        }
    }
    __syncthreads();

    const int kc   = tid >> 5;       // 0..7 k-split
    const int tile = tid & 31;
    const int gt = tile >> 2;        // rows gt + 8*gi
    const int st = tile & 3;         // samples st + 4*si
    const float* wr[4] = { &w_lds[gt][0], &w_lds[8+gt][0], &w_lds[16+gt][0], &w_lds[24+gt][0] };
    const float* hr[4] = { &h_lds[st][0], &h_lds[4+st][0], &h_lds[8+st][0],  &h_lds[12+st][0] };

    float hv_prev = 0.0f;
    size_t ha_prev = 0;

#pragma unroll 1
    for (int tl = 0; tl < CTS; tl++) {
        const int jslot = dir ? (CTS - 1 - tl) : tl;
        const int t = (dir ? (NSC - 1 - sch) : sch) * CTS + jslot;
        const int sc = sch * CTS + tl + 1;
        const int par = sc & 1;

        // top-of-loop issues: drain under the GEMM below
        float xg0 = 0.f, xg1 = 0.f, xg2 = 0.f, xg3 = 0.f;
        if (tid < 128) {
            if (tl > 0) h_all[ha_prev] = hv_prev;
            const float* xp = &xg_ws[(((size_t)(dir * CTS + jslot) * 1024) + h_base + ih_g) * 64 + sbase + s_g];
            xg0 = xp[0];
            xg1 = xp[1 * 256 * 64];
            xg2 = xp[2 * 256 * 64];
            xg3 = xp[3 * 256 * 64];
        }

        float acc[4][4];
#pragma unroll
        for (int gi = 0; gi < 4; gi++)
#pragma unroll
            for (int si = 0; si < 4; si++) acc[gi][si] = 0.0f;

        const int j0 = kc * 32;
#pragma unroll
        for (int m = 0; m < 8; m++) {
            const int jj = j0 + m * 4;
            float4 w4[4], h4[4];
#pragma unroll
            for (int i = 0; i < 4; i++) w4[i] = *(const float4*)(wr[i] + jj);
#pragma unroll
            for (int i = 0; i < 4; i++) h4[i] = *(const float4*)(hr[i] + jj);
#pragma unroll
            for (int gi = 0; gi < 4; gi++)
#pragma unroll
                for (int si = 0; si < 4; si++)
                    acc[gi][si] += w4[gi].x*h4[si].x + w4[gi].y*h4[si].y
                                 + w4[gi].z*h4[si].z + w4[gi].w*h4[si].w;
        }

        // single-phase 8->1 k-split reduction
        if (kc >= 1) {
#pragma unroll
            for (int gi = 0; gi < 4; gi++)
                *(float4*)&red[kc-1][tile][gi*4] =
                    make_float4(acc[gi][0], acc[gi][1], acc[gi][2], acc[gi][3]);
        }
        __syncthreads();
        if (kc == 0) {
#pragma unroll
            for (int p = 0; p < 7; p++)
#pragma unroll
                for (int gi = 0; gi < 4; gi++) {
                    float4 v = *(const float4*)&red[p][tile][gi*4];
                    acc[gi][0] += v.x; acc[gi][1] += v.y; acc[gi][2] += v.z; acc[gi][3] += v.w;
                }
#pragma unroll
            for (int gi = 0; gi < 4; gi++)
#pragma unroll
                for (int si = 0; si < 4; si++)
                    gatebuf[8*gi + gt][4*si + st] = acc[gi][si];
        }
        __syncthreads();

        if (tid < 128) {
            float gI = gatebuf[     ih_g][s_g] + xg0;
            float gF = gatebuf[8  + ih_g][s_g] + xg1;
            float gG = gatebuf[16 + ih_g][s_g] + xg2;
            float gO = gatebuf[24 + ih_g][s_g] + xg3;
            c_val = sigm(gF) * c_val + sigm(gI) * tanhf(gG);
            float hv = sigm(gO) * tanhf(c_val);
            // coalesced: lanes with consecutive ih -> 32-B segments
            __hip_atomic_store(&h_ex[(((size_t)par * 8 + dg) * 16 + s_g) * 256 + h_base + ih_g],
                               hv, __ATOMIC_RELAXED, __HIP_MEMORY_SCOPE_AGENT);
            hv_prev = hv;
            ha_prev = ((size_t)t * 64 + sbase + s_g) * 512 + dir * 256 + h_base + ih_g;
        }
        __syncthreads();   // vmcnt(0) drain -> h_ex committed at coherence point

        if (tid == 0)
            __hip_atomic_store(&flags[dg * 32 + slice], sc, __ATOMIC_RELAXED, __HIP_MEMORY_SCOPE_AGENT);

        // poll wave: nothing else outstanding -> fast first iteration
        if (tid < 64) {
            const int* fp = &flags[dg * 32 + (tid & 31)];
            int spins = 0;
            int v = __hip_atomic_load(fp, __ATOMIC_RELAXED, __HIP_MEMORY_SCOPE_AGENT);
            while (__ballot(v < sc) != 0ull) {
                if (++spins > 8) __builtin_amdgcn_s_sleep(1);
                v = __hip_atomic_load(fp, __ATOMIC_RELAXED, __HIP_MEMORY_SCOPE_AGENT);
                if (spins > (1 << 20)) break;   // safety valve; co-residency guaranteed
            }
        }
        __syncthreads();

        {   // coalesced 8-byte coherent reload -> LDS
            const float* base = &h_ex[(((size_t)par * 8 + dg) * 16) * 256];
#pragma unroll
            for (int i = 0; i < 8; i++) {
                int pos = tid + 256 * i;
                int fo  = pos << 1;
                unsigned long long u64 = __hip_atomic_load(
                    (const unsigned long long*)(base + fo), __ATOMIC_RELAXED, __HIP_MEMORY_SCOPE_AGENT);
                float2 v = __builtin_bit_cast(float2, u64);
                *(float2*)&h_lds[fo >> 8][fo & 255] = v;
            }
        }
        __syncthreads();
    }

    if (tid < 128) {
        h_all[ha_prev] = hv_prev;
        c_state[(size_t)(dir * 64 + sbase + s_g) * 256 + h_base + ih_g] = c_val;
    }
}

// ---------------------------------------------------------------------------
__global__ __launch_bounds__(256) void emis_kernel(
    const float* __restrict__ h_all, const float* __restrict__ w_out,
    const float* __restrict__ b_out, float* __restrict__ emis)
{
    const int row = blockIdx.x * 16 + (threadIdx.x >> 4);
    const int k   = threadIdx.x & 15;
    const float* hr = &h_all[(size_t)row * 512];
    const float* wr = &w_out[(size_t)(k < NTAG ? k : 0) * 512];
    float acc = 0.0f;
#pragma unroll 8
    for (int e = 0; e < 512; e += 4) {
        float4 h4 = *(const float4*)&hr[e];
        float4 w4 = *(const float4*)&wr[e];
        acc += h4.x*w4.x + h4.y*w4.y + h4.z*w4.z + h4.w*w4.w;
    }
    if (k < NTAG) emis[(size_t)row * NTAG + k] = acc + b_out[k];
}

// ---------------------------------------------------------------------------
__global__ __launch_bounds__(64) void viterbi_kernel(
    const float* __restrict__ emis, const float* __restrict__ start_trans,
    const float* __restrict__ end_trans, const float* __restrict__ trans,
    float* __restrict__ out)
{
    const int b = blockIdx.x;
    const int k = threadIdx.x;
    __shared__ float em[T_LEN * NTAG];
    __shared__ unsigned char bp[T_LEN][16];

    for (int t = k; t < T_LEN; t += 64) {
        const float* src = &emis[((size_t)t * 64 + b) * NTAG];
#pragma unroll
        for (int kk = 0; kk < NTAG; kk++)
            em[t * NTAG + kk] = src[kk];
    }
    __syncthreads();

    float tc[NTAG];
#pragma unroll
    for (int kp = 0; kp < NTAG; kp++)
        tc[kp] = (k < NTAG) ? trans[kp * NTAG + k] : 0.0f;

    float score = (k < NTAG) ? (start_trans[k] + em[k]) : -3.0e38f;

    for (int t = 1; t < T_LEN; t++) {
        float best = -3.0e38f;
        int bi = 0;
#pragma unroll
        for (int kp = 0; kp < NTAG; kp++) {
            float v = __shfl(score, kp) + tc[kp];
            if (v > best) { best = v; bi = kp; }   // strict > => first max (jnp.argmax)
        }
        if (k < NTAG) {
            score = best + em[t * NTAG + k];
            bp[t][k] = (unsigned char)bi;
        }
    }
    if (k < NTAG) score += end_trans[k];
    else score = -3.0e38f;
    __syncthreads();

    float bs = -3.0e38f;
    int tag = 0;
#pragma unroll
    for (int kk = 0; kk < NTAG; kk++) {
        float v = __shfl(score, kk);
        if (v > bs) { bs = v; tag = kk; }
    }
    if (k == 0) {
        out[32768 + b] = bs;
        int tg = tag;
        out[b * T_LEN + (T_LEN - 1)] = (float)tg;
        for (int t = T_LEN - 1; t >= 1; t--) {
            tg = bp[t][tg];
            out[b * T_LEN + t - 1] = (float)tg;
        }
    }
}

// ---------------------------------------------------------------------------
extern "C" void kernel_launch(void* const* d_in, const int* in_sizes, int n_in,
                              void* d_out, int out_size, void* d_ws, size_t ws_size,
                              hipStream_t stream)
{
    (void)in_sizes; (void)n_in; (void)out_size; (void)ws_size;
    const int*   x    = (const int*)  d_in[0];
    const float* emb  = (const float*)d_in[1];
    const float* wihf = (const float*)d_in[2];
    const float* whhf = (const float*)d_in[3];
    const float* bihf = (const float*)d_in[4];
    const float* bhhf = (const float*)d_in[5];
    const float* wihb = (const float*)d_in[6];
    const float* whhb = (const float*)d_in[7];
    const float* bihb = (const float*)d_in[8];
    const float* bhhb = (const float*)d_in[9];
    const float* wout = (const float*)d_in[10];
    const float* bout = (const float*)d_in[11];
    const float* stt  = (const float*)d_in[12];
    const float* ent  = (const float*)d_in[13];
    const float* trn  = (const float*)d_in[14];
    float* out = (float*)d_out;

    const size_t XG4_BYTES   = (size_t)2 * CTS * 1024 * 64 * 4;   // 67.11 MB
    const size_t HALL_BYTES  = (size_t)T_LEN * 64 * 512 * 4;      // 67.11 MB
    const size_t HEX_BYTES   = (size_t)2 * 8 * 16 * 256 * 4;      // 256 KB
    const size_t CST_BYTES   = (size_t)2 * 64 * 256 * 4;          // 128 KB
    const size_t EMIS_BYTES  = (size_t)T_LEN * 64 * NTAG * 4;     // 1.70 MB
    const size_t FLAG_BYTES  = 8 * 32 * 4;

    char* ws = (char*)d_ws;
    size_t off = 0;
    float* xg_ws = (float*)(ws + off); off += XG4_BYTES;
    float* h_all = (float*)(ws + off); off += HALL_BYTES;
    float* h_ex  = (float*)(ws + off); off += HEX_BYTES;
    float* c_st  = (float*)(ws + off); off += CST_BYTES;
    float* emis  = (float*)(ws + off); off += EMIS_BYTES;
    int*   flags = (int*)  (ws + off); off += FLAG_BYTES;

    hipMemsetAsync(h_ex,  0, HEX_BYTES, stream);
    hipMemsetAsync(c_st,  0, CST_BYTES, stream);
    hipMemsetAsync(flags, 0, FLAG_BYTES, stream);

    for (int c = 0; c < NSC; c++) {
        xg_gemm4<<<dim3(8, 64, 2), 256, 0, stream>>>(x, emb, wihf, wihb,
                                                     bihf, bhhf, bihb, bhhb, xg_ws, c);
        lstm_chunk4<<<256, 256, 0, stream>>>(xg_ws, whhf, whhb, h_ex, c_st, h_all, flags, c);
    }
    emis_kernel<<<2048, 256, 0, stream>>>(h_all, wout, bout, emis);
    viterbi_kernel<<<64, 64, 0, stream>>>(emis, stt, ent, trn, out);
}

// Round 10
// 3370.444 us; speedup vs baseline: 2.2907x; 1.0112x over previous
//
#include <hip/hip_runtime.h>
#include <stdint.h>
#include <stddef.h>

#define T_LEN  512
#define BATCH  64
#define NTAG   13
#define CT     64
#define NCHUNK 8
#define CTS    128     // super-chunk length
#define NSC    4       // number of super-chunks

__device__ __forceinline__ float sigm(float x) { return 1.0f / (1.0f + expf(-x)); }

// ---------------------------------------------------------------------------
// Kernel 1: input-side GEMM for one 128-step SUPER-chunk (both dirs).
// (R11 version, verified 3385 us total; R13 pipelining was neutral, R15
// CU-partition fusion failed to run -> reverted to this exact kernel.)
// Layout: xg_ws[d][tloc][1024][64], tloc in 0..127 within the super-chunk.
// ---------------------------------------------------------------------------
__global__ __launch_bounds__(256) void xg_gemm4(
    const int* __restrict__ x, const float* __restrict__ emb,
    const float* __restrict__ w_ih_f, const float* __restrict__ w_ih_b,
    const float* __restrict__ b_ih_f, const float* __restrict__ b_hh_f,
    const float* __restrict__ b_ih_b, const float* __restrict__ b_hh_b,
    float* __restrict__ xg_ws, int sch)
{
    const int tid = threadIdx.x;
    const int mt = blockIdx.x;
    const int nt = blockIdx.y;           // 0..63
    const int d  = blockIdx.z;
    const int tbase = (d == 0 ? sch : (NSC - 1 - sch)) * CTS;
    const float* W  = (d == 0) ? w_ih_f : w_ih_b;
    const float* bi = (d == 0) ? b_ih_f : b_ih_b;
    const float* bh = (d == 0) ? b_hh_f : b_hh_b;

    __shared__ __align__(16) float Wl[16][132];
    __shared__ __align__(16) float El[16][132];
    __shared__ int tok[128];

    if (tid < 128) {
        int col = nt * 128 + tid;
        tok[tid] = x[(col & 63) * T_LEN + tbase + (col >> 6)];
    }
    __syncthreads();

    const int r  = tid >> 1;
    const int c8 = (tid & 1) * 8;
    const int tm = tid >> 4;
    const int tn = tid & 15;

    float acc[8][8];
#pragma unroll
    for (int i = 0; i < 8; i++)
#pragma unroll
        for (int jz = 0; jz < 8; jz++) acc[i][jz] = 0.0f;

    const float* wrow = &W[(size_t)(mt * 128 + r) * 256];
    const float* erow = &emb[(size_t)tok[r] * 256];

    for (int kb = 0; kb < 256; kb += 16) {
        float4 w0 = *(const float4*)&wrow[kb + c8];
        float4 w1 = *(const float4*)&wrow[kb + c8 + 4];
        float4 e0 = *(const float4*)&erow[kb + c8];
        float4 e1 = *(const float4*)&erow[kb + c8 + 4];
        __syncthreads();
        Wl[c8+0][r] = w0.x; Wl[c8+1][r] = w0.y; Wl[c8+2][r] = w0.z; Wl[c8+3][r] = w0.w;
        Wl[c8+4][r] = w1.x; Wl[c8+5][r] = w1.y; Wl[c8+6][r] = w1.z; Wl[c8+7][r] = w1.w;
        El[c8+0][r] = e0.x; El[c8+1][r] = e0.y; El[c8+2][r] = e0.z; El[c8+3][r] = e0.w;
        El[c8+4][r] = e1.x; El[c8+5][r] = e1.y; El[c8+6][r] = e1.z; El[c8+7][r] = e1.w;
        __syncthreads();
#pragma unroll
        for (int kk = 0; kk < 16; kk++) {
            float a[8], b[8];
            *(float4*)&a[0] = *(const float4*)&Wl[kk][tm*8];
            *(float4*)&a[4] = *(const float4*)&Wl[kk][tm*8+4];
            *(float4*)&b[0] = *(const float4*)&El[kk][tn*8];
            *(float4*)&b[4] = *(const float4*)&El[kk][tn*8+4];
#pragma unroll
            for (int i = 0; i < 8; i++)
#pragma unroll
                for (int jz = 0; jz < 8; jz++)
                    acc[i][jz] += a[i] * b[jz];
        }
    }

    const int colbase = nt * 128 + tn * 8;
    const int j  = colbase >> 6;         // local timestep 0..127
    const int b0 = colbase & 63;
#pragma unroll
    for (int gi = 0; gi < 8; gi++) {
        int g = mt * 128 + tm * 8 + gi;
        float bias = bi[g] + bh[g];
        float* dst = &xg_ws[(((size_t)(d * CTS + j) * 1024 + g) << 6) + b0];
        float4 v0 = make_float4(acc[gi][0]+bias, acc[gi][1]+bias, acc[gi][2]+bias, acc[gi][3]+bias);
        float4 v1 = make_float4(acc[gi][4]+bias, acc[gi][5]+bias, acc[gi][6]+bias, acc[gi][7]+bias);
        *(float4*)dst       = v0;
        *(float4*)(dst + 4) = v1;
    }
}

// ---------------------------------------------------------------------------
// Kernel 2: persistent chunked LSTM over a 128-step super-chunk.
// Protocol byte-identical to R5 (flags + poll wave + coalesced reload,
// relaxed agent-scope atomics, parity double-buffer, monotonic sc across
// dispatches). FROZEN — four protocol variants (R6/R8/R9/R12) all regressed.
// ---------------------------------------------------------------------------
__global__ __launch_bounds__(256) void lstm_chunk4(
    const float* __restrict__ xg_ws,
    const float* __restrict__ w_hh_f, const float* __restrict__ w_hh_b,
    float* h_ex, float* c_state, float* h_all, int* flags, int sch)
{
    const int tid = threadIdx.x;
    const int bid = blockIdx.x;
    const int dg    = bid & 7;
    const int slice = bid >> 3;      // 0..31
    const int dir = dg & 1;
    const int grp = dg >> 1;
    const int h_base = slice * 8;
    const int sbase  = grp * 16;

    __shared__ __align__(16) float w_lds[32][260];
    __shared__ __align__(16) float h_lds[16][260];
    __shared__ __align__(16) float red[7][32][20];
    __shared__ float gatebuf[32][17];

    const float* W = dir ? w_hh_b : w_hh_f;
    for (int idx = tid; idx < 2048; idx += 256) {     // f4 weight fill
        int f  = idx << 2;
        int rr = f >> 8;
        int c4 = f & 255;
        int row = (rr >> 3) * 256 + h_base + (rr & 7);
        *(float4*)&w_lds[rr][c4] = *(const float4*)&W[(size_t)row * 256 + c4];
    }

    // nonlin-phase mapping (tid<128): ih lane-fastest for coalesced stores
    const int ih_g = tid & 7;
    const int s_g  = tid >> 3;       // 0..15 (for tid<128)
    float c_val = 0.0f;
    if (tid < 128)
        c_val = c_state[(size_t)(dir * 64 + sbase + s_g) * 256 + h_base + ih_g];

    {   // initial h fill from parity-0 buffer (prior super-chunk ends at
        // sc = sch*128, even -> parity 0; sch 0 reads memset zeros)
        const float* base = &h_ex[((size_t)dg * 16) * 256];
#pragma unroll
        for (int i = 0; i < 8; i++) {
            int pos = tid + 256 * i;         // 8-byte units
            int fo  = pos << 1;
            unsigned long long u64 = __hip_atomic_load(
                (const unsigned long long*)(base + fo), __ATOMIC_RELAXED, __HIP_MEMORY_SCOPE_AGENT);
            float2 v = __builtin_bit_cast(float2, u64);
            *(float2*)&h_lds[fo >> 8][fo & 255] = v;
        }
    }
    __syncthreads();

    const int kc   = tid >> 5;       // 0..7 k-split
    const int tile = tid & 31;
    const int gt = tile >> 2;        // rows gt + 8*gi
    const int st = tile & 3;         // samples st + 4*si
    const float* wr[4] = { &w_lds[gt][0], &w_lds[8+gt][0], &w_lds[16+gt][0], &w_lds[24+gt][0] };
    const float* hr[4] = { &h_lds[st][0], &h_lds[4+st][0], &h_lds[8+st][0],  &h_lds[12+st][0] };

    float hv_prev = 0.0f;
    size_t ha_prev = 0;

#pragma unroll 1
    for (int tl = 0; tl < CTS; tl++) {
        const int jslot = dir ? (CTS - 1 - tl) : tl;
        const int t = (dir ? (NSC - 1 - sch) : sch) * CTS + jslot;
        const int sc = sch * CTS + tl + 1;
        const int par = sc & 1;

        // top-of-loop issues: drain under the GEMM below
        float xg0 = 0.f, xg1 = 0.f, xg2 = 0.f, xg3 = 0.f;
        if (tid < 128) {
            if (tl > 0) h_all[ha_prev] = hv_prev;
            const float* xp = &xg_ws[(((size_t)(dir * CTS + jslot) * 1024) + h_base + ih_g) * 64 + sbase + s_g];
            xg0 = xp[0];
            xg1 = xp[1 * 256 * 64];
            xg2 = xp[2 * 256 * 64];
            xg3 = xp[3 * 256 * 64];
        }

        float acc[4][4];
#pragma unroll
        for (int gi = 0; gi < 4; gi++)
#pragma unroll
            for (int si = 0; si < 4; si++) acc[gi][si] = 0.0f;

        const int j0 = kc * 32;
#pragma unroll
        for (int m = 0; m < 8; m++) {
            const int jj = j0 + m * 4;
            float4 w4[4], h4[4];
#pragma unroll
            for (int i = 0; i < 4; i++) w4[i] = *(const float4*)(wr[i] + jj);
#pragma unroll
            for (int i = 0; i < 4; i++) h4[i] = *(const float4*)(hr[i] + jj);
#pragma unroll
            for (int gi = 0; gi < 4; gi++)
#pragma unroll
                for (int si = 0; si < 4; si++)
                    acc[gi][si] += w4[gi].x*h4[si].x + w4[gi].y*h4[si].y
                                 + w4[gi].z*h4[si].z + w4[gi].w*h4[si].w;
        }

        // single-phase 8->1 k-split reduction
        if (kc >= 1) {
#pragma unroll
            for (int gi = 0; gi < 4; gi++)
                *(float4*)&red[kc-1][tile][gi*4] =
                    make_float4(acc[gi][0], acc[gi][1], acc[gi][2], acc[gi][3]);
        }
        __syncthreads();
        if (kc == 0) {
#pragma unroll
            for (int p = 0; p < 7; p++)
#pragma unroll
                for (int gi = 0; gi < 4; gi++) {
                    float4 v = *(const float4*)&red[p][tile][gi*4];
                    acc[gi][0] += v.x; acc[gi][1] += v.y; acc[gi][2] += v.z; acc[gi][3] += v.w;
                }
#pragma unroll
            for (int gi = 0; gi < 4; gi++)
#pragma unroll
                for (int si = 0; si < 4; si++)
                    gatebuf[8*gi + gt][4*si + st] = acc[gi][si];
        }
        __syncthreads();

        if (tid < 128) {
            float gI = gatebuf[     ih_g][s_g] + xg0;
            float gF = gatebuf[8  + ih_g][s_g] + xg1;
            float gG = gatebuf[16 + ih_g][s_g] + xg2;
            float gO = gatebuf[24 + ih_g][s_g] + xg3;
            c_val = sigm(gF) * c_val + sigm(gI) * tanhf(gG);
            float hv = sigm(gO) * tanhf(c_val);
            // coalesced: lanes with consecutive ih -> 32-B segments
            __hip_atomic_store(&h_ex[(((size_t)par * 8 + dg) * 16 + s_g) * 256 + h_base + ih_g],
                               hv, __ATOMIC_RELAXED, __HIP_MEMORY_SCOPE_AGENT);
            hv_prev = hv;
            ha_prev = ((size_t)t * 64 + sbase + s_g) * 512 + dir * 256 + h_base + ih_g;
        }
        __syncthreads();   // vmcnt(0) drain -> h_ex committed at coherence point

        if (tid == 0)
            __hip_atomic_store(&flags[dg * 32 + slice], sc, __ATOMIC_RELAXED, __HIP_MEMORY_SCOPE_AGENT);

        // poll wave: nothing else outstanding -> fast first iteration
        if (tid < 64) {
            const int* fp = &flags[dg * 32 + (tid & 31)];
            int spins = 0;
            int v = __hip_atomic_load(fp, __ATOMIC_RELAXED, __HIP_MEMORY_SCOPE_AGENT);
            while (__ballot(v < sc) != 0ull) {
                if (++spins > 8) __builtin_amdgcn_s_sleep(1);
                v = __hip_atomic_load(fp, __ATOMIC_RELAXED, __HIP_MEMORY_SCOPE_AGENT);
                if (spins > (1 << 20)) break;   // safety valve; co-residency guaranteed
            }
        }
        __syncthreads();

        {   // coalesced 8-byte coherent reload -> LDS
            const float* base = &h_ex[(((size_t)par * 8 + dg) * 16) * 256];
#pragma unroll
            for (int i = 0; i < 8; i++) {
                int pos = tid + 256 * i;
                int fo  = pos << 1;
                unsigned long long u64 = __hip_atomic_load(
                    (const unsigned long long*)(base + fo), __ATOMIC_RELAXED, __HIP_MEMORY_SCOPE_AGENT);
                float2 v = __builtin_bit_cast(float2, u64);
                *(float2*)&h_lds[fo >> 8][fo & 255] = v;
            }
        }
        __syncthreads();
    }

    if (tid < 128) {
        h_all[ha_prev] = hv_prev;
        c_state[(size_t)(dir * 64 + sbase + s_g) * 256 + h_base + ih_g] = c_val;
    }
}

// ---------------------------------------------------------------------------
__global__ __launch_bounds__(256) void emis_kernel(
    const float* __restrict__ h_all, const float* __restrict__ w_out,
    const float* __restrict__ b_out, float* __restrict__ emis)
{
    const int row = blockIdx.x * 16 + (threadIdx.x >> 4);
    const int k   = threadIdx.x & 15;
    const float* hr = &h_all[(size_t)row * 512];
    const float* wr = &w_out[(size_t)(k < NTAG ? k : 0) * 512];
    float acc = 0.0f;
#pragma unroll 8
    for (int e = 0; e < 512; e += 4) {
        float4 h4 = *(const float4*)&hr[e];
        float4 w4 = *(const float4*)&wr[e];
        acc += h4.x*w4.x + h4.y*w4.y + h4.z*w4.z + h4.w*w4.w;
    }
    if (k < NTAG) emis[(size_t)row * NTAG + k] = acc + b_out[k];
}

// ---------------------------------------------------------------------------
__global__ __launch_bounds__(64) void viterbi_kernel(
    const float* __restrict__ emis, const float* __restrict__ start_trans,
    const float* __restrict__ end_trans, const float* __restrict__ trans,
    float* __restrict__ out)
{
    const int b = blockIdx.x;
    const int k = threadIdx.x;
    __shared__ float em[T_LEN * NTAG];
    __shared__ unsigned char bp[T_LEN][16];

    for (int t = k; t < T_LEN; t += 64) {
        const float* src = &emis[((size_t)t * 64 + b) * NTAG];
#pragma unroll
        for (int kk = 0; kk < NTAG; kk++)
            em[t * NTAG + kk] = src[kk];
    }
    __syncthreads();

    float tc[NTAG];
#pragma unroll
    for (int kp = 0; kp < NTAG; kp++)
        tc[kp] = (k < NTAG) ? trans[kp * NTAG + k] : 0.0f;

    float score = (k < NTAG) ? (start_trans[k] + em[k]) : -3.0e38f;

    for (int t = 1; t < T_LEN; t++) {
        float best = -3.0e38f;
        int bi = 0;
#pragma unroll
        for (int kp = 0; kp < NTAG; kp++) {
            float v = __shfl(score, kp) + tc[kp];
            if (v > best) { best = v; bi = kp; }   // strict > => first max (jnp.argmax)
        }
        if (k < NTAG) {
            score = best + em[t * NTAG + k];
            bp[t][k] = (unsigned char)bi;
        }
    }
    if (k < NTAG) score += end_trans[k];
    else score = -3.0e38f;
    __syncthreads();

    float bs = -3.0e38f;
    int tag = 0;
#pragma unroll
    for (int kk = 0; kk < NTAG; kk++) {
        float v = __shfl(score, kk);
        if (v > bs) { bs = v; tag = kk; }
    }
    if (k == 0) {
        out[32768 + b] = bs;
        int tg = tag;
        out[b * T_LEN + (T_LEN - 1)] = (float)tg;
        for (int t = T_LEN - 1; t >= 1; t--) {
            tg = bp[t][tg];
            out[b * T_LEN + t - 1] = (float)tg;
        }
    }
}

// ---------------------------------------------------------------------------
extern "C" void kernel_launch(void* const* d_in, const int* in_sizes, int n_in,
                              void* d_out, int out_size, void* d_ws, size_t ws_size,
                              hipStream_t stream)
{
    (void)in_sizes; (void)n_in; (void)out_size; (void)ws_size;
    const int*   x    = (const int*)  d_in[0];
    const float* emb  = (const float*)d_in[1];
    const float* wihf = (const float*)d_in[2];
    const float* whhf = (const float*)d_in[3];
    const float* bihf = (const float*)d_in[4];
    const float* bhhf = (const float*)d_in[5];
    const float* wihb = (const float*)d_in[6];
    const float* whhb = (const float*)d_in[7];
    const float* bihb = (const float*)d_in[8];
    const float* bhhb = (const float*)d_in[9];
    const float* wout = (const float*)d_in[10];
    const float* bout = (const float*)d_in[11];
    const float* stt  = (const float*)d_in[12];
    const float* ent  = (const float*)d_in[13];
    const float* trn  = (const float*)d_in[14];
    float* out = (float*)d_out;

    const size_t XG4_BYTES   = (size_t)2 * CTS * 1024 * 64 * 4;   // 67.11 MB
    const size_t HALL_BYTES  = (size_t)T_LEN * 64 * 512 * 4;      // 67.11 MB
    const size_t HEX_BYTES   = (size_t)2 * 8 * 16 * 256 * 4;      // 256 KB
    const size_t CST_BYTES   = (size_t)2 * 64 * 256 * 4;          // 128 KB
    const size_t EMIS_BYTES  = (size_t)T_LEN * 64 * NTAG * 4;     // 1.70 MB
    const size_t FLAG_BYTES  = 8 * 32 * 4;

    char* ws = (char*)d_ws;
    size_t off = 0;
    float* xg_ws = (float*)(ws + off); off += XG4_BYTES;
    float* h_all = (float*)(ws + off); off += HALL_BYTES;
    float* h_ex  = (float*)(ws + off); off += HEX_BYTES;
    float* c_st  = (float*)(ws + off); off += CST_BYTES;
    float* emis  = (float*)(ws + off); off += EMIS_BYTES;
    int*   flags = (int*)  (ws + off); off += FLAG_BYTES;

    hipMemsetAsync(h_ex,  0, HEX_BYTES, stream);
    hipMemsetAsync(c_st,  0, CST_BYTES, stream);
    hipMemsetAsync(flags, 0, FLAG_BYTES, stream);

    for (int c = 0; c < NSC; c++) {
        xg_gemm4<<<dim3(8, 64, 2), 256, 0, stream>>>(x, emb, wihf, wihb,
                                                     bihf, bhhf, bihb, bhhb, xg_ws, c);
        lstm_chunk4<<<256, 256, 0, stream>>>(xg_ws, whhf, whhb, h_ex, c_st, h_all, flags, c);
    }
    emis_kernel<<<2048, 256, 0, stream>>>(h_all, wout, bout, emis);
    viterbi_kernel<<<64, 64, 0, stream>>>(emis, stt, ent, trn, out);
}